// Round 6
// baseline (61.277 us; speedup 1.0000x reference)
//
#include <hip/hip_runtime.h>
#include <hip/hip_bf16.h>
#include <stdint.h>

// ---------------------------------------------------------------------------
// out[b,t,a,:] = (state_in[b,t,a,:] @ readin[session[b]]) @ project
// Factored: W_b = readin[session[b]] @ project  (192x256), out_b = X_b @ W_b.
// k1 builds W_t[b][o][i] (bf16, K-major) in d_ws.
// k2: 128x128 tile, BK=32, 3-buffer depth-2 pipeline, counted vmcnt(6),
// one raw s_barrier/step. A reg-staged f32->bf16 (issue-early/write-late,
// T14); B via global_load_lds. LDS [kslot][row] layout, conflict-free reads.
// 48KB LDS -> 3 blocks/CU (12 waves/CU).
// ---------------------------------------------------------------------------

typedef short    bf16x8 __attribute__((ext_vector_type(8)));
typedef float    f32x4  __attribute__((ext_vector_type(4)));
typedef uint32_t u32x4  __attribute__((ext_vector_type(4)));

#define NB    128   // batch
#define MPB   1024  // rows per batch = T*A
#define INF   192   // K of main GEMM
#define RDIM  64
#define OUTF  256

#define WAIT_VM6() asm volatile("s_waitcnt vmcnt(6)" ::: "memory")
#define WAIT_VM0() asm volatile("s_waitcnt vmcnt(0)" ::: "memory")
#define WAIT_LGKM0() asm volatile("s_waitcnt lgkmcnt(0)" ::: "memory")

// round-to-nearest-even f32 -> bf16 bits (scalar path, used in k1)
__device__ __forceinline__ uint16_t f2bf(float f) {
    union { float f; uint32_t u; } v; v.f = f;
    return (uint16_t)((v.u + 0x7fffu + ((v.u >> 16) & 1u)) >> 16);
}
__device__ __forceinline__ uint32_t pack2(float a, float b) {
    return (uint32_t)f2bf(a) | ((uint32_t)f2bf(b) << 16);
}

// packed f32x8 -> bf16x8 via __float22bfloat162_rn (v_cvt_pk_bf16_f32)
__device__ __forceinline__ bf16x8 cvt8(f32x4 a, f32x4 b) {
    union { __hip_bfloat162 h2[4]; bf16x8 h; } r;
    r.h2[0] = __float22bfloat162_rn({a[0], a[1]});
    r.h2[1] = __float22bfloat162_rn({a[2], a[3]});
    r.h2[2] = __float22bfloat162_rn({b[0], b[1]});
    r.h2[3] = __float22bfloat162_rn({b[2], b[3]});
    return r.h;
}

// global -> LDS direct copy, 16B per lane. LDS dest must be wave-uniform base.
__device__ __forceinline__ void gl_lds16(const void* g, void* l) {
    auto gp = (const __attribute__((address_space(1))) uint32_t*)(uintptr_t)g;
    auto lp = (__attribute__((address_space(3))) uint32_t*)(uintptr_t)l;
    __builtin_amdgcn_global_load_lds(gp, lp, 16, 0, 0);
}

// ---------------------------------------------------------------------------
// k1: W_t[b][o][i] = sum_h project[h][o] * readin[session[b]][i][h]
// grid 256 = (b:128) x (o-half:2); block 256 thr (4 waves, 2x2 wave grid)
// (unchanged; proven correct, small cost)
// ---------------------------------------------------------------------------
__global__ __launch_bounds__(256) void k1_build_w(
    const float* __restrict__ readin,    // [512][192][64]
    const float* __restrict__ project,   // [64][256]
    const int*   __restrict__ session,   // [128]
    uint16_t*    __restrict__ Wt)        // [128][256][192] bf16 bits
{
    __shared__ uint16_t Rl[INF * 64];   // [i][h] bf16, XOR-swizzled, 24KB
    __shared__ uint16_t Pl[128 * 64];   // [o][h] bf16, XOR-swizzled, 16KB

    const int b  = blockIdx.x >> 1;
    const int oh = blockIdx.x & 1;
    const int t  = threadIdx.x;
    const float* Rg = readin + (size_t)session[b] * (INF * RDIM);

#pragma unroll
    for (int c = 0; c < 3; ++c) {
        int idx = c * 4096 + t * 16;       // linear into [192][64]
        int row = idx >> 6;
        int kg0 = (idx & 63) >> 3;
        f32x4 v0 = *(const f32x4*)(Rg + idx);
        f32x4 v1 = *(const f32x4*)(Rg + idx + 4);
        f32x4 v2 = *(const f32x4*)(Rg + idx + 8);
        f32x4 v3 = *(const f32x4*)(Rg + idx + 12);
        u32x4 d0, d1;
        d0[0] = pack2(v0[0], v0[1]); d0[1] = pack2(v0[2], v0[3]);
        d0[2] = pack2(v1[0], v1[1]); d0[3] = pack2(v1[2], v1[3]);
        d1[0] = pack2(v2[0], v2[1]); d1[1] = pack2(v2[2], v2[3]);
        d1[2] = pack2(v3[0], v3[1]); d1[3] = pack2(v3[2], v3[3]);
        *(u32x4*)&Rl[row * 64 + (((kg0    ) ^ (row & 7)) << 3)] = d0;
        *(u32x4*)&Rl[row * 64 + (((kg0 + 1) ^ (row & 7)) << 3)] = d1;
    }
    {
        int h  = t >> 2;
        int og = (t & 3) * 32;
        const float* Pg = project + (size_t)h * OUTF + oh * 128 + og;
#pragma unroll
        for (int q = 0; q < 8; ++q) {
            f32x4 v = *(const f32x4*)(Pg + q * 4);
#pragma unroll
            for (int e = 0; e < 4; ++e) {
                int o = og + q * 4 + e;
                Pl[o * 64 + (((h >> 3) ^ (o & 7)) << 3) + (h & 7)] = f2bf(v[e]);
            }
        }
    }
    __syncthreads();

    const int l  = t & 63, w = t >> 6;
    const int wm = w >> 1, wn = w & 1;
    const int lr = l & 15, lk = l >> 4;

    f32x4 acc[4][6];
#pragma unroll
    for (int m = 0; m < 4; ++m)
#pragma unroll
        for (int n = 0; n < 6; ++n) acc[m][n] = f32x4{0.f, 0.f, 0.f, 0.f};

#pragma unroll
    for (int kk = 0; kk < 2; ++kk) {
        int kg = kk * 4 + lk;
        bf16x8 a[4], bb[6];
#pragma unroll
        for (int m = 0; m < 4; ++m) {
            int row = wm * 64 + m * 16 + lr;
            a[m] = *(const bf16x8*)&Pl[row * 64 + ((kg ^ (row & 7)) << 3)];
        }
#pragma unroll
        for (int n = 0; n < 6; ++n) {
            int col = wn * 96 + n * 16 + lr;
            bb[n] = *(const bf16x8*)&Rl[col * 64 + ((kg ^ (col & 7)) << 3)];
        }
#pragma unroll
        for (int m = 0; m < 4; ++m)
#pragma unroll
            for (int n = 0; n < 6; ++n)
                acc[m][n] = __builtin_amdgcn_mfma_f32_16x16x32_bf16(
                    a[m], bb[n], acc[m][n], 0, 0, 0);
    }

    uint16_t* Wb = Wt + ((size_t)b * OUTF + oh * 128) * INF;
#pragma unroll
    for (int m = 0; m < 4; ++m) {
        int o = wm * 64 + m * 16 + lk * 4;
#pragma unroll
        for (int n = 0; n < 6; ++n) {
            int i = wn * 96 + n * 16 + lr;
#pragma unroll
            for (int j = 0; j < 4; ++j)
                Wb[(size_t)(o + j) * INF + i] = f2bf(acc[m][n][j]);
        }
    }
}

// ---------------------------------------------------------------------------
// k2: 128(M) x 128(N) tile, 256 thr = 4 waves (2x2), wave 64x64, BK=32.
// LDS layout (both A and B): [kslot 0..3][row 0..127] units of 16B = 8KB/buf.
//   frag read: lane(lr,lk) -> kslot=lk, rows m*16+lr: 16 contiguous 16B units
//   -> 2-way bank aliasing only (free).
// A: reg-staged. issue 4x global_load_dwordx4 early (thread = row t>>1,
//    k-half t&1); after vmcnt(6): cvt8 -> 2x ds_write_b128. 
// B: global_load_lds, source permuted to [kslot][row] (per-lane source free).
// Pipeline: 3 buffers, depth-2, vmcnt(6) counted (6 vm-instr/wave/stage),
// one s_barrier per step. 48KB LDS -> 3 blocks/CU.
// Grid 2048 = b(128) x mt(8) x nt(2), bijective XCD swizzle (2048%8==0).
// ---------------------------------------------------------------------------
__global__ __launch_bounds__(256, 3) void k2_gemm(
    const float*    __restrict__ X,    // [128][1024][192]
    const uint16_t* __restrict__ Wt,   // [128][256][192] bf16
    float*          __restrict__ Y)    // [128][1024][256]
{
    __shared__ uint8_t As[3][8192];    // 24 KB
    __shared__ uint8_t Bs[3][8192];    // 24 KB

    const int bid0 = blockIdx.x;
    const int bid  = ((bid0 & 7) << 8) | (bid0 >> 3);   // XCD swizzle
    const int b  = bid >> 4;
    const int mt = (bid >> 1) & 7;
    const int nt = bid & 1;
    const int t  = threadIdx.x, l = t & 63, w = t >> 6;

    const float*    Xb = X  + ((size_t)b * MPB  + mt * 128) * INF;
    const uint16_t* Wb = Wt + ((size_t)b * OUTF + nt * 128) * INF;
    float*          Yb = Y  + ((size_t)b * MPB  + mt * 128) * OUTF + nt * 128;

    // ---- A staging geometry: thread -> (row, k-half) ----
    const int ar  = t >> 1;            // 0..127
    const int akh = t & 1;             // 0,1  (k 0..15 / 16..31)
    const float* asrc = Xb + (size_t)ar * INF + akh * 16;
    const int aw0 = (akh * 2    ) * 2048 + ar * 16;   // LDS byte offsets
    const int aw1 = (akh * 2 + 1) * 2048 + ar * 16;

    // ---- B staging geometry: chunk c = w*2+j, unit i = c*64+l ----
    int boff[2], bchunk[2];
#pragma unroll
    for (int j = 0; j < 2; ++j) {
        int c  = w * 2 + j;
        int i  = c * 64 + l;
        int kslot = i >> 7;            // 0..3
        int n  = i & 127;              // row
        boff[j]   = n * INF + kslot * 8;
        bchunk[j] = c;
    }

    f32x4 pa0[4], pa1[4];

    auto issueA = [&](int ks, f32x4* pa) {
        const float* p = asrc + ks * 32;
        pa[0] = *(const f32x4*)(p);
        pa[1] = *(const f32x4*)(p + 4);
        pa[2] = *(const f32x4*)(p + 8);
        pa[3] = *(const f32x4*)(p + 12);
    };
    auto issueB = [&](int ks, int buf) {
#pragma unroll
        for (int j = 0; j < 2; ++j)
            gl_lds16(Wb + boff[j] + ks * 32, &Bs[buf][bchunk[j] * 1024]);
    };
    auto writeA = [&](int buf, const f32x4* pa) {
        *(bf16x8*)&As[buf][aw0] = cvt8(pa[0], pa[1]);
        *(bf16x8*)&As[buf][aw1] = cvt8(pa[2], pa[3]);
    };

    issueA(0, pa0); issueB(0, 0);
    issueA(1, pa1); issueB(1, 1);

    const int wm = w >> 1, wn = w & 1;     // wave grid 2(M) x 2(N)
    const int lr = l & 15, lk = l >> 4;
    const int fofs = lk * 2048 + lr * 16;  // frag base: kslot=lk, +row*16

    f32x4 acc[4][4];
#pragma unroll
    for (int m = 0; m < 4; ++m)
#pragma unroll
        for (int n = 0; n < 4; ++n) acc[m][n] = f32x4{0.f, 0.f, 0.f, 0.f};

#pragma unroll
    for (int ks = 0; ks < 6; ++ks) {
        const int cur = ks % 3;
        if (ks < 5) { WAIT_VM6(); } else { WAIT_VM0(); }
        __builtin_amdgcn_sched_barrier(0);
        writeA(cur, (ks & 1) ? pa1 : pa0);       // A(ks) f32 regs -> bf16 LDS
        WAIT_LGKM0();
        __builtin_amdgcn_s_barrier();
        __builtin_amdgcn_sched_barrier(0);
        if (ks < 4) {                             // stage ks+2 (buffer (ks+2)%3)
            issueA(ks + 2, (ks & 1) ? pa1 : pa0);
            issueB(ks + 2, (ks + 2) % 3);
        }
        __builtin_amdgcn_sched_barrier(0);

        bf16x8 af[4], bfr[4];
#pragma unroll
        for (int m = 0; m < 4; ++m)
            af[m] = *(const bf16x8*)&As[cur][fofs + (wm * 64 + m * 16) * 16];
#pragma unroll
        for (int n = 0; n < 4; ++n)
            bfr[n] = *(const bf16x8*)&Bs[cur][fofs + (wn * 64 + n * 16) * 16];
#pragma unroll
        for (int m = 0; m < 4; ++m)
#pragma unroll
            for (int n = 0; n < 4; ++n)
                acc[m][n] = __builtin_amdgcn_mfma_f32_16x16x32_bf16(
                    af[m], bfr[n], acc[m][n], 0, 0, 0);
    }

    // epilogue: D row=(lane>>4)*4+j, col=lane&15
#pragma unroll
    for (int m = 0; m < 4; ++m) {
        int r0 = wm * 64 + m * 16 + lk * 4;
#pragma unroll
        for (int n = 0; n < 4; ++n) {
            int c0 = wn * 64 + n * 16 + lr;
#pragma unroll
            for (int j = 0; j < 4; ++j)
                Yb[(size_t)(r0 + j) * OUTF + c0] = acc[m][n][j];
        }
    }
}

extern "C" void kernel_launch(void* const* d_in, const int* in_sizes, int n_in,
                              void* d_out, int out_size, void* d_ws, size_t ws_size,
                              hipStream_t stream) {
    (void)in_sizes; (void)n_in; (void)out_size; (void)ws_size;
    const float* state   = (const float*)d_in[0];
    const int*   session = (const int*)  d_in[1];
    const float* readin  = (const float*)d_in[2];
    const float* project = (const float*)d_in[3];
    float*    out = (float*)d_out;
    uint16_t* Wt  = (uint16_t*)d_ws;   // 128*256*192*2 B = 12.6 MB scratch

    hipLaunchKernelGGL(k1_build_w, dim3(256), dim3(256), 0, stream,
                       readin, project, session, Wt);
    hipLaunchKernelGGL(k2_gemm, dim3(2048), dim3(256), 0, stream,
                       state, Wt, out);
}